// Round 4
// baseline (401.493 us; speedup 1.0000x reference)
//
#include <hip/hip_runtime.h>
#include <hip/hip_bf16.h>
#include <cstdint>
#include <cstddef>

#define C_ 128
#define I_ 128
#define W_ 60
#define R_ 36
#define D_ 1024
#define TOPK 20
#define NEGV (-1e30f)
#define EPSV (1e-12f)

typedef __attribute__((ext_vector_type(8))) short bf16x8;
typedef __attribute__((ext_vector_type(4))) float f32x4;
typedef __attribute__((ext_vector_type(4))) int i32x4;

__device__ inline float bf2f(unsigned short u) {
    union { unsigned int i; float f; } x;
    x.i = ((unsigned int)u) << 16;
    return x.f;
}
__device__ inline unsigned short f2bf(float f) {
    __hip_bfloat16 h = __float2bfloat16(f);
    return *(unsigned short*)&h;
}
__device__ inline float wave_sum(float v) {
    #pragma unroll
    for (int o = 32; o; o >>= 1) v += __shfl_xor(v, o);
    return v;
}
__device__ inline float wave_max(float v) {
    #pragma unroll
    for (int o = 32; o; o >>= 1) v = fmaxf(v, __shfl_xor(v, o));
    return v;
}
// load a "float tensor" element that may be stored as f32 or bf16
__device__ inline float loadw(const void* p, int idx, bool isF32) {
    if (isF32) return ((const float*)p)[idx];
    return bf2f(((const unsigned short*)p)[idx]);
}

// ---- dtype probe: bf16 data -> |v|<10; f32-as-bf16 -> random exponents ----
__global__ void detect_dtype(const unsigned short* __restrict__ probe,
                             int* __restrict__ flag) {
    if (threadIdx.x == 0) {
        float mx = 0.f;
        for (int k = 0; k < 256; ++k) {
            float v = __builtin_fabsf(bf2f(probe[k]));
            if (v > mx) mx = v;   // NaN-safe: NaN comparison is false
        }
        *flag = (mx > 1e6f) ? 1 : 0;   // 1 => underlying data is float32
    }
}

// ---- per-row inverse L2 norm over D=1024; one block per row --------------
__global__ __launch_bounds__(256) void rownorm_scale(
    const void* __restrict__ in, float* __restrict__ sc,
    const int* __restrict__ flag) {
    int row = blockIdx.x;
    int t = threadIdx.x;
    bool isF32 = (*flag != 0);
    float v0, v1, v2, v3;
    if (isF32) {
        const float* p = (const float*)in + (size_t)row * D_;
        float4 r = *(const float4*)(p + t * 4);
        v0 = r.x; v1 = r.y; v2 = r.z; v3 = r.w;
    } else {
        const unsigned short* p = (const unsigned short*)in + (size_t)row * D_;
        uint2 raw = *(const uint2*)(p + t * 4);
        v0 = bf2f(raw.x & 0xffff); v1 = bf2f(raw.x >> 16);
        v2 = bf2f(raw.y & 0xffff); v3 = bf2f(raw.y >> 16);
    }
    float ss = v0 * v0 + v1 * v1 + v2 * v2 + v3 * v3;
    ss = wave_sum(ss);
    __shared__ float part[4];
    if ((t & 63) == 0) part[t >> 6] = ss;
    __syncthreads();
    if (t == 0) {
        float tot = part[0] + part[1] + part[2] + part[3];
        sc[row] = 1.0f / fmaxf(sqrtf(tot), EPSV);
    }
}

// ---------------- fused sim + reductions + topk + MLP ----------------------
#define LDA 72          // 64 k + 8 pad (bf16 elems)
#define SS 145          // S row stride in f32

struct __align__(16) Smem {
    union {
        struct { short A[64 * LDA]; short B[144 * LDA]; } st;
        float S[60 * SS];
    } u;
    float scw[60];
    float sci[144];
    float nw[4][36];
    float nr[4][64];
    float w1a[400], w1b[400];
    float b1a[20], b1b[20];
    float w2a[20], w2b[20];
    float b2a, b2b;
};

// topk values are wave-uniform after wave_max -> keep in per-lane registers
__device__ inline float topk_mlp(float val, int lane,
                                 const float* __restrict__ w1,  // LDS, col-read
                                 const float* __restrict__ b1,
                                 const float* __restrict__ w2, float b2v) {
    float tk[TOPK];
    #pragma unroll 1
    for (int k = 0; k < TOPK; ++k) {
        float m = wave_max(val);
        tk[k] = m;
        unsigned long long msk = __ballot(val == m);
        int first = __ffsll(msk) - 1;
        if (first >= 0 && lane == first) val = NEGV;
    }
    float contrib = 0.f;
    if (lane < TOPK) {
        float h = b1[lane];
        #pragma unroll 1
        for (int k = 0; k < TOPK; ++k)
            h += tk[k] * w1[k * TOPK + lane];
        h = fmaxf(h, 0.f);
        contrib = h * w2[lane];
    }
    contrib = wave_sum(contrib);
    return contrib + b2v;
}

__global__ __launch_bounds__(256) void adj_main(
    const void* __restrict__ capRaw, const void* __restrict__ imgRaw,
    const float* __restrict__ scCap, const float* __restrict__ scImg,
    const void* __restrict__ w1_t2i, const void* __restrict__ b1_t2i,
    const void* __restrict__ w2_t2i, const void* __restrict__ b2_t2i,
    const void* __restrict__ w1_i2t, const void* __restrict__ b1_i2t,
    const void* __restrict__ w2_i2t, const void* __restrict__ b2_i2t,
    const int* __restrict__ cap_len, const int* __restrict__ flag,
    float* __restrict__ out) {
    __shared__ Smem sm;
    int tid = threadIdx.x;
    int lane = tid & 63;
    int wid = tid >> 6;
    int bx = blockIdx.x;
    int c = bx >> 5;       // caption
    int g = bx & 31;       // image group (4 images)
    int i0 = g * 4;
    bool isF32 = (*flag != 0);

    // zero the 4 pad rows of A (rows 60..63, 72 shorts each = 144 ints)
    if (tid < 144) ((int*)(sm.u.st.A + 60 * LDA))[tid] = 0;
    // preload row scales
    if (tid < 60) sm.scw[tid] = scCap[c * 60 + tid];
    if (tid < 144) sm.sci[tid] = scImg[i0 * 36 + tid];
    // preload MLP weights as floats
    for (int idx = tid; idx < 400; idx += 256) {
        sm.w1a[idx] = loadw(w1_t2i, idx, isF32);
        sm.w1b[idx] = loadw(w1_i2t, idx, isF32);
    }
    if (tid < 20) {
        sm.b1a[tid] = loadw(b1_t2i, tid, isF32);
        sm.b1b[tid] = loadw(b1_i2t, tid, isF32);
        sm.w2a[tid] = loadw(w2_t2i, tid, isF32);
        sm.w2b[tid] = loadw(w2_i2t, tid, isF32);
    }
    if (tid == 0) { sm.b2a = loadw(b2_t2i, 0, isF32); sm.b2b = loadw(b2_i2t, 0, isF32); }

    f32x4 acc[9];
    #pragma unroll
    for (int t = 0; t < 9; ++t) acc[t] = (f32x4){0.f, 0.f, 0.f, 0.f};

    int quad = lane >> 4;
    int l16 = lane & 15;
    int aoff = (16 * wid + l16) * LDA + quad * 8;
    int boff = l16 * LDA + quad * 8;

    for (int kc = 0; kc < 16; ++kc) {
        __syncthreads();
        int kbase = kc * 64;
        if (isF32) {
            const float* capB = (const float*)capRaw + (size_t)c * W_ * D_;
            const float* imgB = (const float*)imgRaw + (size_t)i0 * R_ * D_;
            for (int idx = tid; idx < 480; idx += 256) {
                int row = idx >> 3, ch = idx & 7;
                const float* p = capB + row * D_ + kbase + ch * 8;
                float4 x = *(const float4*)p;
                float4 y = *(const float4*)(p + 4);
                unsigned int d0 = (unsigned)f2bf(x.x) | ((unsigned)f2bf(x.y) << 16);
                unsigned int d1 = (unsigned)f2bf(x.z) | ((unsigned)f2bf(x.w) << 16);
                unsigned int d2 = (unsigned)f2bf(y.x) | ((unsigned)f2bf(y.y) << 16);
                unsigned int d3 = (unsigned)f2bf(y.z) | ((unsigned)f2bf(y.w) << 16);
                *(i32x4*)(sm.u.st.A + row * LDA + ch * 8) =
                    (i32x4){(int)d0, (int)d1, (int)d2, (int)d3};
            }
            for (int idx = tid; idx < 1152; idx += 256) {
                int row = idx >> 3, ch = idx & 7;
                const float* p = imgB + row * D_ + kbase + ch * 8;
                float4 x = *(const float4*)p;
                float4 y = *(const float4*)(p + 4);
                unsigned int d0 = (unsigned)f2bf(x.x) | ((unsigned)f2bf(x.y) << 16);
                unsigned int d1 = (unsigned)f2bf(x.z) | ((unsigned)f2bf(x.w) << 16);
                unsigned int d2 = (unsigned)f2bf(y.x) | ((unsigned)f2bf(y.y) << 16);
                unsigned int d3 = (unsigned)f2bf(y.z) | ((unsigned)f2bf(y.w) << 16);
                *(i32x4*)(sm.u.st.B + row * LDA + ch * 8) =
                    (i32x4){(int)d0, (int)d1, (int)d2, (int)d3};
            }
        } else {
            const short* capB = (const short*)capRaw + (size_t)c * W_ * D_;
            const short* imgB = (const short*)imgRaw + (size_t)i0 * R_ * D_;
            for (int idx = tid; idx < 480; idx += 256) {
                int row = idx >> 3, ch = idx & 7;
                i32x4 v = *(const i32x4*)(capB + row * D_ + kbase + ch * 8);
                *(i32x4*)(sm.u.st.A + row * LDA + ch * 8) = v;
            }
            for (int idx = tid; idx < 1152; idx += 256) {
                int row = idx >> 3, ch = idx & 7;
                i32x4 v = *(const i32x4*)(imgB + row * D_ + kbase + ch * 8);
                *(i32x4*)(sm.u.st.B + row * LDA + ch * 8) = v;
            }
        }
        __syncthreads();
        #pragma unroll
        for (int ks = 0; ks < 2; ++ks) {
            bf16x8 a = *(const bf16x8*)(sm.u.st.A + aoff + 32 * ks);
            #pragma unroll
            for (int t = 0; t < 9; ++t) {
                bf16x8 b = *(const bf16x8*)(sm.u.st.B + t * (16 * LDA) + boff + 32 * ks);
                acc[t] = __builtin_amdgcn_mfma_f32_16x16x32_bf16(a, b, acc[t], 0, 0, 0);
            }
        }
    }
    __syncthreads();
    // scale to normalized sim, apply leaky relu, write S
    // C/D layout: col=lane&15, row=quad*4+reg
    #pragma unroll
    for (int t = 0; t < 9; ++t) {
        #pragma unroll
        for (int v = 0; v < 4; ++v) {
            int row = 16 * wid + quad * 4 + v;
            int col = 16 * t + l16;
            if (row < 60) {
                float x = acc[t][v] * sm.scw[row] * sm.sci[col];
                x = x >= 0.f ? x : 0.1f * x;
                sm.u.S[row * SS + col] = x;
            }
        }
    }
    __syncthreads();

    // -------- epilogue: wave `wid` handles image j = wid --------
    int j = wid;
    int i = i0 + j;
    int base = 36 * j;
    int L = cap_len[c];
    if (L < 1) L = 1;
    if (L > 60) L = 60;
    int Msel = L > TOPK ? L : TOPK;

    // t2i norms: per r, over w < Msel
    if (lane < 36) {
        float ssum = 0.f;
        for (int w = 0; w < Msel; ++w) {
            float v = sm.u.S[w * SS + base + lane];
            ssum += v * v;
        }
        sm.nw[j][lane] = 1.0f / fmaxf(sqrtf(ssum), EPSV);
    }
    // i2t norms: per w, over all r
    if (lane < 60) {
        float ssum = 0.f;
        for (int r = 0; r < 36; ++r) {
            float v = sm.u.S[lane * SS + base + r];
            ssum += v * v;
        }
        sm.nr[j][lane] = 1.0f / fmaxf(sqrtf(ssum), EPSV);
    }

    // row_sim (lane = w)
    float rs = NEGV;
    if (lane < Msel) {
        float m = -3.4e38f;
        for (int r = 0; r < 36; ++r) {
            float v = sm.u.S[lane * SS + base + r];
            m = fmaxf(m, v * sm.nw[j][r]);
        }
        rs = m;
    }
    float msum = (lane < L) ? rs : 0.f;
    msum = wave_sum(msum);
    float row_mean = msum / (float)L;

    float t2i = topk_mlp(rs, lane, sm.w1a, sm.b1a, sm.w2a, sm.b2a) + row_mean;
    if (lane == 0) {
        out[(size_t)c * 128 + i] = t2i;
        out[2 * 16384 + (size_t)c * 128 + i] = row_mean;
    }

    // col_sim (lane = r)
    float cs = NEGV;
    if (lane < 36) {
        float m = -3.4e38f;
        for (int w = 0; w < L; ++w) {
            float v = sm.u.S[w * SS + base + lane];
            m = fmaxf(m, v * sm.nr[j][w]);
        }
        cs = m;
    }
    float csum = (lane < 36) ? cs : 0.f;
    csum = wave_sum(csum);
    float col_mean = csum / 36.f;

    float i2t = topk_mlp(cs, lane, sm.w1b, sm.b1b, sm.w2b, sm.b2b) + col_mean;
    if (lane == 0) {
        out[16384 + (size_t)i * 128 + c] = i2t;
        out[3 * 16384 + (size_t)i * 128 + c] = col_mean;
    }
}

extern "C" void kernel_launch(void* const* d_in, const int* in_sizes, int n_in,
                              void* d_out, int out_size, void* d_ws, size_t ws_size,
                              hipStream_t stream) {
    (void)in_sizes; (void)n_in; (void)out_size; (void)ws_size;
    const void* img    = d_in[0];
    const void* cap    = d_in[1];
    const int* cap_len = (const int*)d_in[10];
    float* out = (float*)d_out;

    int*   flag  = (int*)d_ws;              // [0]
    float* scImg = (float*)d_ws + 16;       // 4608 floats
    float* scCap = scImg + I_ * R_;         // 7680 floats (total ~49 KB)

    detect_dtype<<<1, 64, 0, stream>>>((const unsigned short*)img, flag);
    rownorm_scale<<<I_ * R_, 256, 0, stream>>>(img, scImg, flag);
    rownorm_scale<<<C_ * W_, 256, 0, stream>>>(cap, scCap, flag);
    adj_main<<<C_ * 32, 256, 0, stream>>>(cap, img, scCap, scImg,
                                          d_in[2], d_in[3], d_in[4], d_in[5],
                                          d_in[6], d_in[7], d_in[8], d_in[9],
                                          cap_len, flag, out);
}

// Round 5
// 401.316 us; speedup vs baseline: 1.0004x; 1.0004x over previous
//
#include <hip/hip_runtime.h>
#include <hip/hip_bf16.h>
#include <cstdint>
#include <cstddef>

#define C_ 128
#define I_ 128
#define W_ 60
#define R_ 36
#define D_ 1024
#define TOPK 20
#define NEGV (-1e30f)
#define EPSV (1e-12f)

typedef __attribute__((ext_vector_type(8))) short bf16x8;
typedef __attribute__((ext_vector_type(4))) float f32x4;
typedef __attribute__((ext_vector_type(4))) int i32x4;

__device__ inline float bf2f(unsigned short u) {
    union { unsigned int i; float f; } x;
    x.i = ((unsigned int)u) << 16;
    return x.f;
}
__device__ inline unsigned short f2bf(float f) {
    __hip_bfloat16 h = __float2bfloat16(f);
    return *(unsigned short*)&h;
}
__device__ inline float wave_sum(float v) {
    #pragma unroll
    for (int o = 32; o; o >>= 1) v += __shfl_xor(v, o);
    return v;
}
__device__ inline float wave_max(float v) {
    #pragma unroll
    for (int o = 32; o; o >>= 1) v = fmaxf(v, __shfl_xor(v, o));
    return v;
}
__device__ inline float loadw(const void* p, int idx, bool isF32) {
    if (isF32) return ((const float*)p)[idx];
    return bf2f(((const unsigned short*)p)[idx]);
}

// ---- dtype probe: bf16 data -> |v|<10; f32-as-bf16 -> random exponents ----
__global__ void detect_dtype(const unsigned short* __restrict__ probe,
                             int* __restrict__ flag) {
    if (threadIdx.x == 0) {
        float mx = 0.f;
        for (int k = 0; k < 256; ++k) {
            float v = __builtin_fabsf(bf2f(probe[k]));
            if (v > mx) mx = v;
        }
        *flag = (mx > 1e6f) ? 1 : 0;
    }
}

// ---- fused normalize + bf16 convert: row -> normalized bf16 row in ws -----
__global__ __launch_bounds__(256) void prep_norm(
    const void* __restrict__ img, const void* __restrict__ cap,
    unsigned short* __restrict__ outN, const int* __restrict__ flag) {
    int row = blockIdx.x;              // 0..12287: img rows then cap rows
    int t = threadIdx.x;
    bool isF32 = (*flag != 0);
    const void* src; int srow;
    if (row < I_ * R_) { src = img; srow = row; }
    else               { src = cap; srow = row - I_ * R_; }
    float v0, v1, v2, v3;
    if (isF32) {
        const float* p = (const float*)src + (size_t)srow * D_ + t * 4;
        float4 r = *(const float4*)p;
        v0 = r.x; v1 = r.y; v2 = r.z; v3 = r.w;
    } else {
        const unsigned short* p = (const unsigned short*)src + (size_t)srow * D_ + t * 4;
        uint2 raw = *(const uint2*)p;
        v0 = bf2f(raw.x & 0xffff); v1 = bf2f(raw.x >> 16);
        v2 = bf2f(raw.y & 0xffff); v3 = bf2f(raw.y >> 16);
    }
    float ss = v0 * v0 + v1 * v1 + v2 * v2 + v3 * v3;
    ss = wave_sum(ss);
    __shared__ float part[4];
    if ((t & 63) == 0) part[t >> 6] = ss;
    __syncthreads();
    float tot = part[0] + part[1] + part[2] + part[3];
    float s = 1.0f / fmaxf(sqrtf(tot), EPSV);
    uint2 w;
    w.x = (unsigned)f2bf(v0 * s) | ((unsigned)f2bf(v1 * s) << 16);
    w.y = (unsigned)f2bf(v2 * s) | ((unsigned)f2bf(v3 * s) << 16);
    *(uint2*)(outN + (size_t)row * D_ + t * 4) = w;
}

// topk values are wave-uniform after wave_max -> per-lane registers/scratch
__device__ inline float topk_mlp(float val, int lane,
                                 const float* __restrict__ w1,
                                 const float* __restrict__ b1,
                                 const float* __restrict__ w2, float b2v) {
    float tk[TOPK];
    #pragma unroll 1
    for (int k = 0; k < TOPK; ++k) {
        float m = wave_max(val);
        tk[k] = m;
        unsigned long long msk = __ballot(val == m);
        int first = __ffsll(msk) - 1;
        if (first >= 0 && lane == first) val = NEGV;
    }
    float contrib = 0.f;
    if (lane < TOPK) {
        float h = b1[lane];
        #pragma unroll 1
        for (int k = 0; k < TOPK; ++k)
            h += tk[k] * w1[k * TOPK + lane];
        h = fmaxf(h, 0.f);
        contrib = h * w2[lane];
    }
    contrib = wave_sum(contrib);
    return contrib + b2v;
}

// =================== NEW main kernel: CB=2 x IB=4 tile =====================
#define LDA2 72      // 64 k + 8 pad (bf16)
#define SSB 148      // S (bf16) row stride in shorts

struct __align__(16) Smem2 {
    union {
        struct { short A[128 * LDA2]; short B[144 * LDA2]; } st;  // 39168 B
        unsigned short Sb[120 * SSB];                              // 35520 B
    } u;
    float nw[8][36];
    float nr[8][60];
    float w1a[400], w1b[400], b1a[20], b1b[20], w2a[20], w2b[20];
    float b2a, b2b;
};

__global__ __launch_bounds__(256, 3) void adj_main2(
    const unsigned short* __restrict__ capN, const unsigned short* __restrict__ imgN,
    const void* __restrict__ w1_t2i, const void* __restrict__ b1_t2i,
    const void* __restrict__ w2_t2i, const void* __restrict__ b2_t2i,
    const void* __restrict__ w1_i2t, const void* __restrict__ b1_i2t,
    const void* __restrict__ w2_i2t, const void* __restrict__ b2_i2t,
    const int* __restrict__ cap_len, const int* __restrict__ flag,
    float* __restrict__ out) {
    __shared__ Smem2 sm;
    int tid = threadIdx.x;
    int lane = tid & 63;
    int wid = tid >> 6;
    int bx = blockIdx.x;
    int cg = bx & 63;          // ig-major: XCD = cg % 8 -> A-slice L2-resident,
    int ig = bx >> 6;          // one hot img panel per XCD at a time
    int c0 = cg * 2;
    int i0 = ig * 4;
    bool isF32 = (*flag != 0);

    for (int idx = tid; idx < 400; idx += 256) {
        sm.w1a[idx] = loadw(w1_t2i, idx, isF32);
        sm.w1b[idx] = loadw(w1_i2t, idx, isF32);
    }
    if (tid < 20) {
        sm.b1a[tid] = loadw(b1_t2i, tid, isF32);
        sm.b1b[tid] = loadw(b1_i2t, tid, isF32);
        sm.w2a[tid] = loadw(w2_t2i, tid, isF32);
        sm.w2b[tid] = loadw(w2_i2t, tid, isF32);
    }
    if (tid == 0) { sm.b2a = loadw(b2_t2i, 0, isF32); sm.b2b = loadw(b2_i2t, 0, isF32); }

    f32x4 acc0[9], acc1[9];
    #pragma unroll
    for (int t = 0; t < 9; ++t) {
        acc0[t] = (f32x4){0.f, 0.f, 0.f, 0.f};
        acc1[t] = (f32x4){0.f, 0.f, 0.f, 0.f};
    }

    const unsigned short* capB = capN + (size_t)c0 * 60 * D_;
    const unsigned short* imgB = imgN + (size_t)i0 * 36 * D_;

    int quad = lane >> 4;
    int l16 = lane & 15;

    for (int kc = 0; kc < 16; ++kc) {
        __syncthreads();
        int kb = kc * 64;
        // stage A: 128 LDS rows (120 real, 8 dup of row 119); B: 144 rows
        for (int idx = tid; idx < 2176; idx += 256) {
            int s = idx;
            if (s < 1024) {
                int row = s >> 3, ch = s & 7;
                int ar = row < 120 ? row : 119;
                *(i32x4*)(sm.u.st.A + row * LDA2 + ch * 8) =
                    *(const i32x4*)(capB + (size_t)ar * D_ + kb + ch * 8);
            } else {
                s -= 1024;
                int row = s >> 3, ch = s & 7;
                *(i32x4*)(sm.u.st.B + row * LDA2 + ch * 8) =
                    *(const i32x4*)(imgB + (size_t)row * D_ + kb + ch * 8);
            }
        }
        __syncthreads();
        #pragma unroll
        for (int ks = 0; ks < 2; ++ks) {
            bf16x8 a0 = *(const bf16x8*)(sm.u.st.A + (wid * 16 + l16) * LDA2 + quad * 8 + 32 * ks);
            bf16x8 a1 = *(const bf16x8*)(sm.u.st.A + ((wid + 4) * 16 + l16) * LDA2 + quad * 8 + 32 * ks);
            #pragma unroll
            for (int t = 0; t < 9; ++t) {
                bf16x8 b = *(const bf16x8*)(sm.u.st.B + (t * 16 + l16) * LDA2 + quad * 8 + 32 * ks);
                acc0[t] = __builtin_amdgcn_mfma_f32_16x16x32_bf16(a0, b, acc0[t], 0, 0, 0);
                acc1[t] = __builtin_amdgcn_mfma_f32_16x16x32_bf16(a1, b, acc1[t], 0, 0, 0);
            }
        }
    }
    __syncthreads();
    // leaky-relu + write S (bf16). C/D layout: col=lane&15, row=quad*4+reg
    #pragma unroll
    for (int t = 0; t < 9; ++t) {
        int col = 16 * t + l16;
        #pragma unroll
        for (int v = 0; v < 4; ++v) {
            int row0 = wid * 16 + quad * 4 + v;          // 0..63, all real
            float x0 = acc0[t][v];
            x0 = x0 >= 0.f ? x0 : 0.1f * x0;
            sm.u.Sb[row0 * SSB + col] = f2bf(x0);
            int row1 = 64 + wid * 16 + quad * 4 + v;     // 64..127
            if (row1 < 120) {
                float x1 = acc1[t][v];
                x1 = x1 >= 0.f ? x1 : 0.1f * x1;
                sm.u.Sb[row1 * SSB + col] = f2bf(x1);
            }
        }
    }
    __syncthreads();

    // ---- epilogue: wave handles pairs p = wid, wid+4; p -> (cc, j) --------
    #pragma unroll 1
    for (int pp = 0; pp < 2; ++pp) {
        int p = wid + pp * 4;      // 0..7
        int cc = p >> 2, j = p & 3;
        int c = c0 + cc, i = i0 + j;
        int sbase = cc * 60;       // S row offset
        int cbase = j * 36;        // S col offset
        int L = cap_len[c];
        if (L < 1) L = 1;
        if (L > 60) L = 60;
        int Msel = L > TOPK ? L : TOPK;

        if (lane < 36) {
            float ssum = 0.f;
            for (int w = 0; w < Msel; ++w) {
                float v = bf2f(sm.u.Sb[(sbase + w) * SSB + cbase + lane]);
                ssum += v * v;
            }
            sm.nw[p][lane] = 1.0f / fmaxf(sqrtf(ssum), EPSV);
        }
        if (lane < 60) {
            float ssum = 0.f;
            for (int r = 0; r < 36; ++r) {
                float v = bf2f(sm.u.Sb[(sbase + lane) * SSB + cbase + r]);
                ssum += v * v;
            }
            sm.nr[p][lane] = 1.0f / fmaxf(sqrtf(ssum), EPSV);
        }

        // row_sim (lane = w)
        float rs = NEGV;
        if (lane < Msel) {
            float m = -3.4e38f;
            for (int r = 0; r < 36; ++r) {
                float v = bf2f(sm.u.Sb[(sbase + lane) * SSB + cbase + r]);
                m = fmaxf(m, v * sm.nw[p][r]);
            }
            rs = m;
        }
        float msum = (lane < L) ? rs : 0.f;
        msum = wave_sum(msum);
        float row_mean = msum / (float)L;

        float t2i = topk_mlp(rs, lane, sm.w1a, sm.b1a, sm.w2a, sm.b2a) + row_mean;
        if (lane == 0) {
            out[(size_t)c * 128 + i] = t2i;
            out[2 * 16384 + (size_t)c * 128 + i] = row_mean;
        }

        // col_sim (lane = r)
        float cs = NEGV;
        if (lane < 36) {
            float m = -3.4e38f;
            for (int w = 0; w < L; ++w) {
                float v = bf2f(sm.u.Sb[(sbase + w) * SSB + cbase + lane]);
                m = fmaxf(m, v * sm.nr[p][w]);
            }
            cs = m;
        }
        float csum = (lane < 36) ? cs : 0.f;
        csum = wave_sum(csum);
        float col_mean = csum / 36.f;

        float i2t = topk_mlp(cs, lane, sm.w1b, sm.b1b, sm.w2b, sm.b2b) + col_mean;
        if (lane == 0) {
            out[16384 + (size_t)i * 128 + c] = i2t;
            out[3 * 16384 + (size_t)i * 128 + c] = col_mean;
        }
    }
}

// ================= FALLBACK (round-4 proven path, small ws) ================
__global__ __launch_bounds__(256) void rownorm_scale(
    const void* __restrict__ in, float* __restrict__ sc,
    const int* __restrict__ flag) {
    int row = blockIdx.x;
    int t = threadIdx.x;
    bool isF32 = (*flag != 0);
    float v0, v1, v2, v3;
    if (isF32) {
        const float* p = (const float*)in + (size_t)row * D_;
        float4 r = *(const float4*)(p + t * 4);
        v0 = r.x; v1 = r.y; v2 = r.z; v3 = r.w;
    } else {
        const unsigned short* p = (const unsigned short*)in + (size_t)row * D_;
        uint2 raw = *(const uint2*)(p + t * 4);
        v0 = bf2f(raw.x & 0xffff); v1 = bf2f(raw.x >> 16);
        v2 = bf2f(raw.y & 0xffff); v3 = bf2f(raw.y >> 16);
    }
    float ss = v0 * v0 + v1 * v1 + v2 * v2 + v3 * v3;
    ss = wave_sum(ss);
    __shared__ float part[4];
    if ((t & 63) == 0) part[t >> 6] = ss;
    __syncthreads();
    if (t == 0) {
        float tot = part[0] + part[1] + part[2] + part[3];
        sc[row] = 1.0f / fmaxf(sqrtf(tot), EPSV);
    }
}

#define LDA 72
#define SS 145
struct __align__(16) Smem {
    union {
        struct { short A[64 * LDA]; short B[144 * LDA]; } st;
        float S[60 * SS];
    } u;
    float scw[60];
    float sci[144];
    float nw[4][36];
    float nr[4][64];
    float w1a[400], w1b[400];
    float b1a[20], b1b[20];
    float w2a[20], w2b[20];
    float b2a, b2b;
};

__global__ __launch_bounds__(256) void adj_main(
    const void* __restrict__ capRaw, const void* __restrict__ imgRaw,
    const float* __restrict__ scCap, const float* __restrict__ scImg,
    const void* __restrict__ w1_t2i, const void* __restrict__ b1_t2i,
    const void* __restrict__ w2_t2i, const void* __restrict__ b2_t2i,
    const void* __restrict__ w1_i2t, const void* __restrict__ b1_i2t,
    const void* __restrict__ w2_i2t, const void* __restrict__ b2_i2t,
    const int* __restrict__ cap_len, const int* __restrict__ flag,
    float* __restrict__ out) {
    __shared__ Smem sm;
    int tid = threadIdx.x;
    int lane = tid & 63;
    int wid = tid >> 6;
    int bx = blockIdx.x;
    int c = bx >> 5;
    int g = bx & 31;
    int i0 = g * 4;
    bool isF32 = (*flag != 0);

    if (tid < 144) ((int*)(sm.u.st.A + 60 * LDA))[tid] = 0;
    if (tid < 60) sm.scw[tid] = scCap[c * 60 + tid];
    if (tid < 144) sm.sci[tid] = scImg[i0 * 36 + tid];
    for (int idx = tid; idx < 400; idx += 256) {
        sm.w1a[idx] = loadw(w1_t2i, idx, isF32);
        sm.w1b[idx] = loadw(w1_i2t, idx, isF32);
    }
    if (tid < 20) {
        sm.b1a[tid] = loadw(b1_t2i, tid, isF32);
        sm.b1b[tid] = loadw(b1_i2t, tid, isF32);
        sm.w2a[tid] = loadw(w2_t2i, tid, isF32);
        sm.w2b[tid] = loadw(w2_i2t, tid, isF32);
    }
    if (tid == 0) { sm.b2a = loadw(b2_t2i, 0, isF32); sm.b2b = loadw(b2_i2t, 0, isF32); }

    f32x4 acc[9];
    #pragma unroll
    for (int t = 0; t < 9; ++t) acc[t] = (f32x4){0.f, 0.f, 0.f, 0.f};

    int quad = lane >> 4;
    int l16 = lane & 15;
    int aoff = (16 * wid + l16) * LDA + quad * 8;
    int boff = l16 * LDA + quad * 8;

    for (int kc = 0; kc < 16; ++kc) {
        __syncthreads();
        int kbase = kc * 64;
        if (isF32) {
            const float* capB = (const float*)capRaw + (size_t)c * W_ * D_;
            const float* imgB = (const float*)imgRaw + (size_t)i0 * R_ * D_;
            for (int idx = tid; idx < 480; idx += 256) {
                int row = idx >> 3, ch = idx & 7;
                const float* p = capB + row * D_ + kbase + ch * 8;
                float4 x = *(const float4*)p;
                float4 y = *(const float4*)(p + 4);
                unsigned int d0 = (unsigned)f2bf(x.x) | ((unsigned)f2bf(x.y) << 16);
                unsigned int d1 = (unsigned)f2bf(x.z) | ((unsigned)f2bf(x.w) << 16);
                unsigned int d2 = (unsigned)f2bf(y.x) | ((unsigned)f2bf(y.y) << 16);
                unsigned int d3 = (unsigned)f2bf(y.z) | ((unsigned)f2bf(y.w) << 16);
                *(i32x4*)(sm.u.st.A + row * LDA + ch * 8) =
                    (i32x4){(int)d0, (int)d1, (int)d2, (int)d3};
            }
            for (int idx = tid; idx < 1152; idx += 256) {
                int row = idx >> 3, ch = idx & 7;
                const float* p = imgB + row * D_ + kbase + ch * 8;
                float4 x = *(const float4*)p;
                float4 y = *(const float4*)(p + 4);
                unsigned int d0 = (unsigned)f2bf(x.x) | ((unsigned)f2bf(x.y) << 16);
                unsigned int d1 = (unsigned)f2bf(x.z) | ((unsigned)f2bf(x.w) << 16);
                unsigned int d2 = (unsigned)f2bf(y.x) | ((unsigned)f2bf(y.y) << 16);
                unsigned int d3 = (unsigned)f2bf(y.z) | ((unsigned)f2bf(y.w) << 16);
                *(i32x4*)(sm.u.st.B + row * LDA + ch * 8) =
                    (i32x4){(int)d0, (int)d1, (int)d2, (int)d3};
            }
        } else {
            const short* capB = (const short*)capRaw + (size_t)c * W_ * D_;
            const short* imgB = (const short*)imgRaw + (size_t)i0 * R_ * D_;
            for (int idx = tid; idx < 480; idx += 256) {
                int row = idx >> 3, ch = idx & 7;
                i32x4 v = *(const i32x4*)(capB + row * D_ + kbase + ch * 8);
                *(i32x4*)(sm.u.st.A + row * LDA + ch * 8) = v;
            }
            for (int idx = tid; idx < 1152; idx += 256) {
                int row = idx >> 3, ch = idx & 7;
                i32x4 v = *(const i32x4*)(imgB + row * D_ + kbase + ch * 8);
                *(i32x4*)(sm.u.st.B + row * LDA + ch * 8) = v;
            }
        }
        __syncthreads();
        #pragma unroll
        for (int ks = 0; ks < 2; ++ks) {
            bf16x8 a = *(const bf16x8*)(sm.u.st.A + aoff + 32 * ks);
            #pragma unroll
            for (int t = 0; t < 9; ++t) {
                bf16x8 b = *(const bf16x8*)(sm.u.st.B + t * (16 * LDA) + boff + 32 * ks);
                acc[t] = __builtin_amdgcn_mfma_f32_16x16x32_bf16(a, b, acc[t], 0, 0, 0);
            }
        }
    }
    __syncthreads();
    #pragma unroll
    for (int t = 0; t < 9; ++t) {
        #pragma unroll
        for (int v = 0; v < 4; ++v) {
            int row = 16 * wid + quad * 4 + v;
            int col = 16 * t + l16;
            if (row < 60) {
                float x = acc[t][v] * sm.scw[row] * sm.sci[col];
                x = x >= 0.f ? x : 0.1f * x;
                sm.u.S[row * SS + col] = x;
            }
        }
    }
    __syncthreads();

    int j = wid;
    int i = i0 + j;
    int base = 36 * j;
    int L = cap_len[c];
    if (L < 1) L = 1;
    if (L > 60) L = 60;
    int Msel = L > TOPK ? L : TOPK;

    if (lane < 36) {
        float ssum = 0.f;
        for (int w = 0; w < Msel; ++w) {
            float v = sm.u.S[w * SS + base + lane];
            ssum += v * v;
        }
        sm.nw[j][lane] = 1.0f / fmaxf(sqrtf(ssum), EPSV);
    }
    if (lane < 60) {
        float ssum = 0.f;
        for (int r = 0; r < 36; ++r) {
            float v = sm.u.S[lane * SS + base + r];
            ssum += v * v;
        }
        sm.nr[j][lane] = 1.0f / fmaxf(sqrtf(ssum), EPSV);
    }

    float rs = NEGV;
    if (lane < Msel) {
        float m = -3.4e38f;
        for (int r = 0; r < 36; ++r) {
            float v = sm.u.S[lane * SS + base + r];
            m = fmaxf(m, v * sm.nw[j][r]);
        }
        rs = m;
    }
    float msum = (lane < L) ? rs : 0.f;
    msum = wave_sum(msum);
    float row_mean = msum / (float)L;

    float t2i = topk_mlp(rs, lane, sm.w1a, sm.b1a, sm.w2a, sm.b2a) + row_mean;
    if (lane == 0) {
        out[(size_t)c * 128 + i] = t2i;
        out[2 * 16384 + (size_t)c * 128 + i] = row_mean;
    }

    float cs = NEGV;
    if (lane < 36) {
        float m = -3.4e38f;
        for (int w = 0; w < L; ++w) {
            float v = sm.u.S[w * SS + base + lane];
            m = fmaxf(m, v * sm.nr[j][w]);
        }
        cs = m;
    }
    float csum = (lane < 36) ? cs : 0.f;
    csum = wave_sum(csum);
    float col_mean = csum / 36.f;

    float i2t = topk_mlp(cs, lane, sm.w1b, sm.b1b, sm.w2b, sm.b2b) + col_mean;
    if (lane == 0) {
        out[16384 + (size_t)i * 128 + c] = i2t;
        out[3 * 16384 + (size_t)i * 128 + c] = col_mean;
    }
}

extern "C" void kernel_launch(void* const* d_in, const int* in_sizes, int n_in,
                              void* d_out, int out_size, void* d_ws, size_t ws_size,
                              hipStream_t stream) {
    (void)in_sizes; (void)n_in; (void)out_size;
    const void* img    = d_in[0];
    const void* cap    = d_in[1];
    const int* cap_len = (const int*)d_in[10];
    float* out = (float*)d_out;

    int* flag = (int*)d_ws;
    const size_t needed = 256 + (size_t)(I_ * R_ + C_ * W_) * D_ * 2;

    detect_dtype<<<1, 64, 0, stream>>>((const unsigned short*)img, flag);

    if (ws_size >= needed) {
        // fast path: pre-normalized bf16 in ws
        unsigned short* outN = (unsigned short*)((char*)d_ws + 256);
        const unsigned short* imgN = outN;                          // 4608 rows
        const unsigned short* capN = outN + (size_t)I_ * R_ * D_;   // 7680 rows
        prep_norm<<<I_ * R_ + C_ * W_, 256, 0, stream>>>(img, cap, outN, flag);
        adj_main2<<<2048, 256, 0, stream>>>(capN, imgN,
                                            d_in[2], d_in[3], d_in[4], d_in[5],
                                            d_in[6], d_in[7], d_in[8], d_in[9],
                                            cap_len, flag, out);
    } else {
        // fallback: proven round-4 path (49 KB ws)
        float* scImg = (float*)d_ws + 16;
        float* scCap = scImg + I_ * R_;
        rownorm_scale<<<I_ * R_, 256, 0, stream>>>(img, scImg, flag);
        rownorm_scale<<<C_ * W_, 256, 0, stream>>>(cap, scCap, flag);
        adj_main<<<C_ * 32, 256, 0, stream>>>(cap, img, scCap, scImg,
                                              d_in[2], d_in[3], d_in[4], d_in[5],
                                              d_in[6], d_in[7], d_in[8], d_in[9],
                                              cap_len, flag, out);
    }
}

// Round 6
// 284.997 us; speedup vs baseline: 1.4088x; 1.4081x over previous
//
#include <hip/hip_runtime.h>
#include <hip/hip_bf16.h>
#include <cstdint>
#include <cstddef>

#define C_ 128
#define I_ 128
#define W_ 60
#define R_ 36
#define D_ 1024
#define TOPK 20
#define NEGV (-1e30f)
#define EPSV (1e-12f)

typedef __attribute__((ext_vector_type(8))) short bf16x8;
typedef __attribute__((ext_vector_type(4))) float f32x4;
typedef __attribute__((ext_vector_type(4))) int i32x4;

__device__ inline float bf2f(unsigned short u) {
    union { unsigned int i; float f; } x;
    x.i = ((unsigned int)u) << 16;
    return x.f;
}
__device__ inline unsigned short f2bf(float f) {
    __hip_bfloat16 h = __float2bfloat16(f);
    return *(unsigned short*)&h;
}
__device__ inline float wave_sum(float v) {
    #pragma unroll
    for (int o = 32; o; o >>= 1) v += __shfl_xor(v, o);
    return v;
}
__device__ inline float wave_max(float v) {
    #pragma unroll
    for (int o = 32; o; o >>= 1) v = fmaxf(v, __shfl_xor(v, o));
    return v;
}
__device__ inline float loadw(const void* p, int idx, bool isF32) {
    if (isF32) return ((const float*)p)[idx];
    return bf2f(((const unsigned short*)p)[idx]);
}
// async global -> LDS DMA, 16 B per lane; LDS dest = wave-uniform base + lane*16
__device__ inline void dma16(const void* g, void* l) {
    __builtin_amdgcn_global_load_lds(
        (const __attribute__((address_space(1))) unsigned int*)g,
        (__attribute__((address_space(3))) unsigned int*)l, 16, 0, 0);
}

// ==== prep: inline dtype detect + l2norm rows -> bf16 in ws; blk0 stages MLP ====
__global__ __launch_bounds__(256) void prep_norm2(
    const void* __restrict__ img, const void* __restrict__ cap,
    const void* __restrict__ w1_t2i, const void* __restrict__ b1_t2i,
    const void* __restrict__ w2_t2i, const void* __restrict__ b2_t2i,
    const void* __restrict__ w1_i2t, const void* __restrict__ b1_i2t,
    const void* __restrict__ w2_i2t, const void* __restrict__ b2_i2t,
    unsigned short* __restrict__ outN, float* __restrict__ wsW) {
    int t = threadIdx.x;
    int row = blockIdx.x;            // 0..4607 img, 4608..12287 cap
    // dtype probe: first 1 KB of img; f32-as-bf16 low halves have huge exponents
    unsigned int probe = ((const unsigned int*)img)[t];
    float pa = fmaxf(__builtin_fabsf(bf2f(probe & 0xffff)),
                     __builtin_fabsf(bf2f(probe >> 16)));
    bool isF32 = __syncthreads_or(pa > 1e6f) != 0;

    const void* src; int srow;
    if (row < I_ * R_) { src = img; srow = row; }
    else               { src = cap; srow = row - I_ * R_; }
    float v0, v1, v2, v3;
    if (isF32) {
        const float* p = (const float*)src + (size_t)srow * D_ + t * 4;
        float4 r = *(const float4*)p;
        v0 = r.x; v1 = r.y; v2 = r.z; v3 = r.w;
    } else {
        const unsigned short* p = (const unsigned short*)src + (size_t)srow * D_ + t * 4;
        uint2 raw = *(const uint2*)p;
        v0 = bf2f(raw.x & 0xffff); v1 = bf2f(raw.x >> 16);
        v2 = bf2f(raw.y & 0xffff); v3 = bf2f(raw.y >> 16);
    }
    float ss = v0 * v0 + v1 * v1 + v2 * v2 + v3 * v3;
    ss = wave_sum(ss);
    __shared__ float part[4];
    if ((t & 63) == 0) part[t >> 6] = ss;
    __syncthreads();
    float tot = part[0] + part[1] + part[2] + part[3];
    float s = 1.0f / fmaxf(sqrtf(tot), EPSV);
    uint2 w;
    w.x = (unsigned)f2bf(v0 * s) | ((unsigned)f2bf(v1 * s) << 16);
    w.y = (unsigned)f2bf(v2 * s) | ((unsigned)f2bf(v3 * s) << 16);
    *(uint2*)(outN + (size_t)row * D_ + t * 4) = w;

    // block 0: stage MLP weights to ws as f32
    // layout: [0,400) w1a | [400,800) w1b | [800,820) b1a | [820,840) b1b
    //         [840,860) w2a | [860,880) w2b | [880] b2a | [881] b2b
    if (blockIdx.x == 0) {
        for (int idx = t; idx < 400; idx += 256) {
            wsW[idx]       = loadw(w1_t2i, idx, isF32);
            wsW[400 + idx] = loadw(w1_i2t, idx, isF32);
        }
        if (t < 20) {
            wsW[800 + t] = loadw(b1_t2i, t, isF32);
            wsW[820 + t] = loadw(b1_i2t, t, isF32);
            wsW[840 + t] = loadw(w2_t2i, t, isF32);
            wsW[860 + t] = loadw(w2_i2t, t, isF32);
        }
        if (t == 0) { wsW[880] = loadw(b2_t2i, 0, isF32); wsW[881] = loadw(b2_i2t, 0, isF32); }
    }
}

// topk values are wave-uniform after wave_max -> per-lane registers
__device__ inline float topk_mlp(float val, int lane,
                                 const float* __restrict__ w1,
                                 const float* __restrict__ b1,
                                 const float* __restrict__ w2, float b2v) {
    float tk[TOPK];
    #pragma unroll 1
    for (int k = 0; k < TOPK; ++k) {
        float m = wave_max(val);
        tk[k] = m;
        unsigned long long msk = __ballot(val == m);
        int first = __ffsll(msk) - 1;
        if (first >= 0 && lane == first) val = NEGV;
    }
    float contrib = 0.f;
    if (lane < TOPK) {
        float h = b1[lane];
        #pragma unroll 1
        for (int k = 0; k < TOPK; ++k)
            h += tk[k] * w1[k * TOPK + lane];
        h = fmaxf(h, 0.f);
        contrib = h * w2[lane];
    }
    contrib = wave_sum(contrib);
    return contrib + b2v;
}

// ========== main: DMA-staged, XOR-swizzled, CB=2 x IB=4 tile ==========
#define SSB 148      // S (bf16) row stride

struct __align__(16) Smem3 {
    union {
        struct { short A[128 * 64]; short B[144 * 64]; } st;  // 34816 B, pad-free
        unsigned short Sb[120 * SSB];                          // 35520 B
    } u;
    float nw[8][36];
    float nr[8][60];
    float wts[882];
};

__global__ __launch_bounds__(256, 3) void adj_main3(
    const unsigned short* __restrict__ capN, const unsigned short* __restrict__ imgN,
    const float* __restrict__ wsW, const int* __restrict__ cap_len,
    float* __restrict__ out) {
    __shared__ Smem3 sm;
    int tid = threadIdx.x;
    int lane = tid & 63;
    int wid = tid >> 6;
    int bx = blockIdx.x;
    int cg = bx & 63;          // XCD = cg % 8: caption slice L2-resident per XCD
    int ig = bx >> 6;
    int c0 = cg * 2;
    int i0 = ig * 4;

    for (int idx = tid; idx < 882; idx += 256) sm.wts[idx] = wsW[idx];

    f32x4 acc0[9], acc1[9];
    #pragma unroll
    for (int t = 0; t < 9; ++t) {
        acc0[t] = (f32x4){0.f, 0.f, 0.f, 0.f};
        acc1[t] = (f32x4){0.f, 0.f, 0.f, 0.f};
    }

    const unsigned short* capB = capN + (size_t)c0 * 60 * D_;
    const unsigned short* imgB = imgN + (size_t)i0 * 36 * D_;

    int quad = lane >> 4;
    int l16 = lane & 15;
    // DMA lane mapping: within a wave-op, lane covers LDS row wo*8 + (lane>>3),
    // physical chunk lane&7; swizzled logical chunk q8 = (lane&7) ^ (lane>>3 & 7)
    int sub = lane >> 3;
    int q8 = (lane & 7) ^ sub;

    __syncthreads();   // wts staged (also first-iter LDS safety)
    for (int kc = 0; kc < 16; ++kc) {
        int kb = kc * 64;
        // A: 16 wave-ops (128 rows; 120 real + 8 dup of row 119)
        #pragma unroll
        for (int u = 0; u < 4; ++u) {
            int wo = (wid << 2) + u;
            int r = (wo << 3) + sub;
            int ar = r < 120 ? r : 119;
            dma16(capB + (size_t)ar * D_ + kb + q8 * 8,
                  (char*)sm.u.st.A + (wo << 10));
        }
        // B: 18 wave-ops (144 rows)
        for (int wo = wid; wo < 18; wo += 4) {
            int r = (wo << 3) + sub;
            dma16(imgB + (size_t)r * D_ + kb + q8 * 8,
                  (char*)sm.u.st.B + (wo << 10));
        }
        __syncthreads();   // DMA complete
        #pragma unroll
        for (int ks = 0; ks < 2; ++ks) {
            int swz = ((quad + 4 * ks) ^ (l16 & 7)) << 3;   // swizzled k-chunk (shorts)
            int rowA0 = (wid << 4) + l16;
            int rowA1 = ((wid + 4) << 4) + l16;
            bf16x8 a0 = *(const bf16x8*)(sm.u.st.A + rowA0 * 64 + swz);
            bf16x8 a1 = *(const bf16x8*)(sm.u.st.A + rowA1 * 64 + swz);
            #pragma unroll
            for (int t = 0; t < 9; ++t) {
                int rowB = (t << 4) + l16;
                bf16x8 b = *(const bf16x8*)(sm.u.st.B + rowB * 64 + swz);
                acc0[t] = __builtin_amdgcn_mfma_f32_16x16x32_bf16(a0, b, acc0[t], 0, 0, 0);
                acc1[t] = __builtin_amdgcn_mfma_f32_16x16x32_bf16(a1, b, acc1[t], 0, 0, 0);
            }
        }
        __syncthreads();   // compute done before next DMA overwrites
    }
    // leaky-relu + write S (bf16). C/D layout: col=lane&15, row=quad*4+reg
    #pragma unroll
    for (int t = 0; t < 9; ++t) {
        int col = 16 * t + l16;
        #pragma unroll
        for (int v = 0; v < 4; ++v) {
            int row0 = wid * 16 + quad * 4 + v;          // 0..63
            float x0 = acc0[t][v];
            x0 = x0 >= 0.f ? x0 : 0.1f * x0;
            sm.u.Sb[row0 * SSB + col] = f2bf(x0);
            int row1 = 64 + wid * 16 + quad * 4 + v;     // 64..127
            if (row1 < 120) {
                float x1 = acc1[t][v];
                x1 = x1 >= 0.f ? x1 : 0.1f * x1;
                sm.u.Sb[row1 * SSB + col] = f2bf(x1);
            }
        }
    }
    __syncthreads();

    const float* w1a = sm.wts;        const float* w1b = sm.wts + 400;
    const float* b1a = sm.wts + 800;  const float* b1b = sm.wts + 820;
    const float* w2a = sm.wts + 840;  const float* w2b = sm.wts + 860;
    float b2a = sm.wts[880], b2b = sm.wts[881];

    // ---- epilogue: wave handles pairs p = wid, wid+4; p -> (cc, j) --------
    #pragma unroll 1
    for (int pp = 0; pp < 2; ++pp) {
        int p = wid + pp * 4;
        int cc = p >> 2, j = p & 3;
        int c = c0 + cc, i = i0 + j;
        int sbase = cc * 60;
        int cbase = j * 36;
        int L = cap_len[c];
        if (L < 1) L = 1;
        if (L > 60) L = 60;
        int Msel = L > TOPK ? L : TOPK;

        if (lane < 36) {
            float ssum = 0.f;
            for (int w = 0; w < Msel; ++w) {
                float v = bf2f(sm.u.Sb[(sbase + w) * SSB + cbase + lane]);
                ssum += v * v;
            }
            sm.nw[p][lane] = 1.0f / fmaxf(sqrtf(ssum), EPSV);
        }
        if (lane < 60) {
            float ssum = 0.f;
            for (int r = 0; r < 36; ++r) {
                float v = bf2f(sm.u.Sb[(sbase + lane) * SSB + cbase + r]);
                ssum += v * v;
            }
            sm.nr[p][lane] = 1.0f / fmaxf(sqrtf(ssum), EPSV);
        }

        // row_sim (lane = w)
        float rs = NEGV;
        if (lane < Msel) {
            float m = -3.4e38f;
            for (int r = 0; r < 36; ++r) {
                float v = bf2f(sm.u.Sb[(sbase + lane) * SSB + cbase + r]);
                m = fmaxf(m, v * sm.nw[p][r]);
            }
            rs = m;
        }
        float msum = (lane < L) ? rs : 0.f;
        msum = wave_sum(msum);
        float row_mean = msum / (float)L;

        float t2i = topk_mlp(rs, lane, w1a, b1a, w2a, b2a) + row_mean;
        if (lane == 0) {
            out[(size_t)c * 128 + i] = t2i;
            out[2 * 16384 + (size_t)c * 128 + i] = row_mean;
        }

        // col_sim (lane = r)
        float cs = NEGV;
        if (lane < 36) {
            float m = -3.4e38f;
            for (int w = 0; w < L; ++w) {
                float v = bf2f(sm.u.Sb[(sbase + w) * SSB + cbase + lane]);
                m = fmaxf(m, v * sm.nr[p][w]);
            }
            cs = m;
        }
        float csum = (lane < 36) ? cs : 0.f;
        csum = wave_sum(csum);
        float col_mean = csum / 36.f;

        float i2t = topk_mlp(cs, lane, w1b, b1b, w2b, b2b) + col_mean;
        if (lane == 0) {
            out[16384 + (size_t)i * 128 + c] = i2t;
            out[3 * 16384 + (size_t)i * 128 + c] = col_mean;
        }
    }
}

// ================= FALLBACK (round-4 proven path, small ws) ================
__global__ void detect_dtype(const unsigned short* __restrict__ probe,
                             int* __restrict__ flag) {
    if (threadIdx.x == 0) {
        float mx = 0.f;
        for (int k = 0; k < 256; ++k) {
            float v = __builtin_fabsf(bf2f(probe[k]));
            if (v > mx) mx = v;
        }
        *flag = (mx > 1e6f) ? 1 : 0;
    }
}

__global__ __launch_bounds__(256) void rownorm_scale(
    const void* __restrict__ in, float* __restrict__ sc,
    const int* __restrict__ flag) {
    int row = blockIdx.x;
    int t = threadIdx.x;
    bool isF32 = (*flag != 0);
    float v0, v1, v2, v3;
    if (isF32) {
        const float* p = (const float*)in + (size_t)row * D_;
        float4 r = *(const float4*)(p + t * 4);
        v0 = r.x; v1 = r.y; v2 = r.z; v3 = r.w;
    } else {
        const unsigned short* p = (const unsigned short*)in + (size_t)row * D_;
        uint2 raw = *(const uint2*)(p + t * 4);
        v0 = bf2f(raw.x & 0xffff); v1 = bf2f(raw.x >> 16);
        v2 = bf2f(raw.y & 0xffff); v3 = bf2f(raw.y >> 16);
    }
    float ss = v0 * v0 + v1 * v1 + v2 * v2 + v3 * v3;
    ss = wave_sum(ss);
    __shared__ float part[4];
    if ((t & 63) == 0) part[t >> 6] = ss;
    __syncthreads();
    if (t == 0) {
        float tot = part[0] + part[1] + part[2] + part[3];
        sc[row] = 1.0f / fmaxf(sqrtf(tot), EPSV);
    }
}

#define LDA 72
#define SS 145
struct __align__(16) Smem {
    union {
        struct { short A[64 * LDA]; short B[144 * LDA]; } st;
        float S[60 * SS];
    } u;
    float scw[60];
    float sci[144];
    float nw[4][36];
    float nr[4][64];
    float w1a[400], w1b[400];
    float b1a[20], b1b[20];
    float w2a[20], w2b[20];
    float b2a, b2b;
};

__global__ __launch_bounds__(256) void adj_main(
    const void* __restrict__ capRaw, const void* __restrict__ imgRaw,
    const float* __restrict__ scCap, const float* __restrict__ scImg,
    const void* __restrict__ w1_t2i, const void* __restrict__ b1_t2i,
    const void* __restrict__ w2_t2i, const void* __restrict__ b2_t2i,
    const void* __restrict__ w1_i2t, const void* __restrict__ b1_i2t,
    const void* __restrict__ w2_i2t, const void* __restrict__ b2_i2t,
    const int* __restrict__ cap_len, const int* __restrict__ flag,
    float* __restrict__ out) {
    __shared__ Smem sm;
    int tid = threadIdx.x;
    int lane = tid & 63;
    int wid = tid >> 6;
    int bx = blockIdx.x;
    int c = bx >> 5;
    int g = bx & 31;
    int i0 = g * 4;
    bool isF32 = (*flag != 0);

    if (tid < 144) ((int*)(sm.u.st.A + 60 * LDA))[tid] = 0;
    if (tid < 60) sm.scw[tid] = scCap[c * 60 + tid];
    if (tid < 144) sm.sci[tid] = scImg[i0 * 36 + tid];
    for (int idx = tid; idx < 400; idx += 256) {
        sm.w1a[idx] = loadw(w1_t2i, idx, isF32);
        sm.w1b[idx] = loadw(w1_i2t, idx, isF32);
    }
    if (tid < 20) {
        sm.b1a[tid] = loadw(b1_t2i, tid, isF32);
        sm.b1b[tid] = loadw(b1_i2t, tid, isF32);
        sm.w2a[tid] = loadw(w2_t2i, tid, isF32);
        sm.w2b[tid] = loadw(w2_i2t, tid, isF32);
    }
    if (tid == 0) { sm.b2a = loadw(b2_t2i, 0, isF32); sm.b2b = loadw(b2_i2t, 0, isF32); }

    f32x4 acc[9];
    #pragma unroll
    for (int t = 0; t < 9; ++t) acc[t] = (f32x4){0.f, 0.f, 0.f, 0.f};

    int quad = lane >> 4;
    int l16 = lane & 15;
    int aoff = (16 * wid + l16) * LDA + quad * 8;
    int boff = l16 * LDA + quad * 8;

    for (int kc = 0; kc < 16; ++kc) {
        __syncthreads();
        int kbase = kc * 64;
        if (isF32) {
            const float* capB = (const float*)capRaw + (size_t)c * W_ * D_;
            const float* imgB = (const float*)imgRaw + (size_t)i0 * R_ * D_;
            for (int idx = tid; idx < 480; idx += 256) {
                int row = idx >> 3, ch = idx & 7;
                const float* p = capB + row * D_ + kbase + ch * 8;
                float4 x = *(const float4*)p;
                float4 y = *(const float4*)(p + 4);
                unsigned int d0 = (unsigned)f2bf(x.x) | ((unsigned)f2bf(x.y) << 16);
                unsigned int d1 = (unsigned)f2bf(x.z) | ((unsigned)f2bf(x.w) << 16);
                unsigned int d2 = (unsigned)f2bf(y.x) | ((unsigned)f2bf(y.y) << 16);
                unsigned int d3 = (unsigned)f2bf(y.z) | ((unsigned)f2bf(y.w) << 16);
                *(i32x4*)(sm.u.st.A + row * LDA + ch * 8) =
                    (i32x4){(int)d0, (int)d1, (int)d2, (int)d3};
            }
            for (int idx = tid; idx < 1152; idx += 256) {
                int row = idx >> 3, ch = idx & 7;
                const float* p = imgB + row * D_ + kbase + ch * 8;
                float4 x = *(const float4*)p;
                float4 y = *(const float4*)(p + 4);
                unsigned int d0 = (unsigned)f2bf(x.x) | ((unsigned)f2bf(x.y) << 16);
                unsigned int d1 = (unsigned)f2bf(x.z) | ((unsigned)f2bf(x.w) << 16);
                unsigned int d2 = (unsigned)f2bf(y.x) | ((unsigned)f2bf(y.y) << 16);
                unsigned int d3 = (unsigned)f2bf(y.z) | ((unsigned)f2bf(y.w) << 16);
                *(i32x4*)(sm.u.st.B + row * LDA + ch * 8) =
                    (i32x4){(int)d0, (int)d1, (int)d2, (int)d3};
            }
        } else {
            const short* capB = (const short*)capRaw + (size_t)c * W_ * D_;
            const short* imgB = (const short*)imgRaw + (size_t)i0 * R_ * D_;
            for (int idx = tid; idx < 480; idx += 256) {
                int row = idx >> 3, ch = idx & 7;
                i32x4 v = *(const i32x4*)(capB + row * D_ + kbase + ch * 8);
                *(i32x4*)(sm.u.st.A + row * LDA + ch * 8) = v;
            }
            for (int idx = tid; idx < 1152; idx += 256) {
                int row = idx >> 3, ch = idx & 7;
                i32x4 v = *(const i32x4*)(imgB + row * D_ + kbase + ch * 8);
                *(i32x4*)(sm.u.st.B + row * LDA + ch * 8) = v;
            }
        }
        __syncthreads();
        #pragma unroll
        for (int ks = 0; ks < 2; ++ks) {
            bf16x8 a = *(const bf16x8*)(sm.u.st.A + aoff + 32 * ks);
            #pragma unroll
            for (int t = 0; t < 9; ++t) {
                bf16x8 b = *(const bf16x8*)(sm.u.st.B + t * (16 * LDA) + boff + 32 * ks);
                acc[t] = __builtin_amdgcn_mfma_f32_16x16x32_bf16(a, b, acc[t], 0, 0, 0);
            }
        }
    }
    __syncthreads();
    #pragma unroll
    for (int t = 0; t < 9; ++t) {
        #pragma unroll
        for (int v = 0; v < 4; ++v) {
            int row = 16 * wid + quad * 4 + v;
            int col = 16 * t + l16;
            if (row < 60) {
                float x = acc[t][v] * sm.scw[row] * sm.sci[col];
                x = x >= 0.f ? x : 0.1f * x;
                sm.u.S[row * SS + col] = x;
            }
        }
    }
    __syncthreads();

    int j = wid;
    int i = i0 + j;
    int base = 36 * j;
    int L = cap_len[c];
    if (L < 1) L = 1;
    if (L > 60) L = 60;
    int Msel = L > TOPK ? L : TOPK;

    if (lane < 36) {
        float ssum = 0.f;
        for (int w = 0; w < Msel; ++w) {
            float v = sm.u.S[w * SS + base + lane];
            ssum += v * v;
        }
        sm.nw[j][lane] = 1.0f / fmaxf(sqrtf(ssum), EPSV);
    }
    if (lane < 60) {
        float ssum = 0.f;
        for (int r = 0; r < 36; ++r) {
            float v = sm.u.S[lane * SS + base + r];
            ssum += v * v;
        }
        sm.nr[j][lane] = 1.0f / fmaxf(sqrtf(ssum), EPSV);
    }

    float rs = NEGV;
    if (lane < Msel) {
        float m = -3.4e38f;
        for (int r = 0; r < 36; ++r) {
            float v = sm.u.S[lane * SS + base + r];
            m = fmaxf(m, v * sm.nw[j][r]);
        }
        rs = m;
    }
    float msum = (lane < L) ? rs : 0.f;
    msum = wave_sum(msum);
    float row_mean = msum / (float)L;

    float t2i = topk_mlp(rs, lane, sm.w1a, sm.b1a, sm.w2a, sm.b2a) + row_mean;
    if (lane == 0) {
        out[(size_t)c * 128 + i] = t2i;
        out[2 * 16384 + (size_t)c * 128 + i] = row_mean;
    }

    float cs = NEGV;
    if (lane < 36) {
        float m = -3.4e38f;
        for (int w = 0; w < L; ++w) {
            float v = sm.u.S[w * SS + base + lane];
            m = fmaxf(m, v * sm.nr[j][w]);
        }
        cs = m;
    }
    float csum = (lane < 36) ? cs : 0.f;
    csum = wave_sum(csum);
    float col_mean = csum / 36.f;

    float i2t = topk_mlp(cs, lane, sm.w1b, sm.b1b, sm.w2b, sm.b2b) + col_mean;
    if (lane == 0) {
        out[16384 + (size_t)i * 128 + c] = i2t;
        out[3 * 16384 + (size_t)i * 128 + c] = col_mean;
    }
}

extern "C" void kernel_launch(void* const* d_in, const int* in_sizes, int n_in,
                              void* d_out, int out_size, void* d_ws, size_t ws_size,
                              hipStream_t stream) {
    (void)in_sizes; (void)n_in; (void)out_size;
    const void* img    = d_in[0];
    const void* cap    = d_in[1];
    const int* cap_len = (const int*)d_in[10];
    float* out = (float*)d_out;

    const size_t needed = 4096 + (size_t)(I_ * R_ + C_ * W_) * D_ * 2;

    if (ws_size >= needed) {
        float* wsW = (float*)d_ws;                               // 882 f32
        unsigned short* outN = (unsigned short*)((char*)d_ws + 4096);
        const unsigned short* imgN = outN;                       // 4608 rows
        const unsigned short* capN = outN + (size_t)I_ * R_ * D_; // 7680 rows
        prep_norm2<<<I_ * R_ + C_ * W_, 256, 0, stream>>>(
            img, cap,
            d_in[2], d_in[3], d_in[4], d_in[5],
            d_in[6], d_in[7], d_in[8], d_in[9],
            outN, wsW);
        adj_main3<<<2048, 256, 0, stream>>>(capN, imgN, wsW, cap_len, out);
    } else {
        int* flag = (int*)d_ws;
        float* scImg = (float*)d_ws + 16;
        float* scCap = scImg + I_ * R_;
        detect_dtype<<<1, 64, 0, stream>>>((const unsigned short*)img, flag);
        rownorm_scale<<<I_ * R_, 256, 0, stream>>>(img, scImg, flag);
        rownorm_scale<<<C_ * W_, 256, 0, stream>>>(cap, scCap, flag);
        adj_main<<<C_ * 32, 256, 0, stream>>>(cap, img, scCap, scImg,
                                              d_in[2], d_in[3], d_in[4], d_in[5],
                                              d_in[6], d_in[7], d_in[8], d_in[9],
                                              cap_len, flag, out);
    }
}

// Round 7
// 219.707 us; speedup vs baseline: 1.8274x; 1.2972x over previous
//
#include <hip/hip_runtime.h>
#include <hip/hip_bf16.h>
#include <cstdint>
#include <cstddef>

#define C_ 128
#define I_ 128
#define W_ 60
#define R_ 36
#define D_ 1024
#define TOPK 20
#define NEGV (-1e30f)
#define EPSV (1e-12f)

typedef __attribute__((ext_vector_type(8))) short bf16x8;
typedef __attribute__((ext_vector_type(4))) float f32x4;
typedef __attribute__((ext_vector_type(4))) int i32x4;

__device__ inline float bf2f(unsigned short u) {
    union { unsigned int i; float f; } x;
    x.i = ((unsigned int)u) << 16;
    return x.f;
}
__device__ inline unsigned short f2bf(float f) {
    __hip_bfloat16 h = __float2bfloat16(f);
    return *(unsigned short*)&h;
}
__device__ inline float wave_sum(float v) {
    #pragma unroll
    for (int o = 32; o; o >>= 1) v += __shfl_xor(v, o);
    return v;
}
__device__ inline float wave_max(float v) {
    #pragma unroll
    for (int o = 32; o; o >>= 1) v = fmaxf(v, __shfl_xor(v, o));
    return v;
}
__device__ inline float loadw(const void* p, int idx, bool isF32) {
    if (isF32) return ((const float*)p)[idx];
    return bf2f(((const unsigned short*)p)[idx]);
}
// async global -> LDS DMA, 16 B per lane; LDS dest = wave-uniform base + lane*16
__device__ inline void dma16(const void* g, void* l) {
    __builtin_amdgcn_global_load_lds(
        (const __attribute__((address_space(1))) unsigned int*)g,
        (__attribute__((address_space(3))) unsigned int*)l, 16, 0, 0);
}

// full 64-lane bitonic sort, descending (lane 0 = max)
__device__ inline float bitonic64_desc(float v, int lane) {
    #pragma unroll
    for (int k = 2; k <= 64; k <<= 1) {
        #pragma unroll
        for (int j = k >> 1; j > 0; j >>= 1) {
            float o = __shfl_xor(v, j);
            bool keepMax = (((lane & k) == 0) == ((lane & j) == 0));
            v = keepMax ? fmaxf(v, o) : fminf(v, o);
        }
    }
    return v;
}

// sorted top-20 + 20x20 MLP; weights read from global (L1/L2-hot f32 staging)
__device__ inline float topk_mlp2(float val, int lane,
                                  const float* __restrict__ w1g,
                                  const float* __restrict__ b1g,
                                  const float* __restrict__ w2g, float b2v) {
    float s = bitonic64_desc(val, lane);
    float h = 0.f;
    if (lane < TOPK) h = b1g[lane];
    #pragma unroll
    for (int k = 0; k < TOPK; ++k) {
        float sk = __shfl(s, k);
        if (lane < TOPK) h += sk * w1g[k * TOPK + lane];
    }
    float contrib = 0.f;
    if (lane < TOPK) contrib = fmaxf(h, 0.f) * w2g[lane];
    contrib = wave_sum(contrib);
    return contrib + b2v;
}

// ==== prep: one wave per row; l2norm -> bf16 in ws; blk0 stages MLP wts ====
__global__ __launch_bounds__(256) void prep_norm3(
    const void* __restrict__ img, const void* __restrict__ cap,
    const void* __restrict__ w1_t2i, const void* __restrict__ b1_t2i,
    const void* __restrict__ w2_t2i, const void* __restrict__ b2_t2i,
    const void* __restrict__ w1_i2t, const void* __restrict__ b1_i2t,
    const void* __restrict__ w2_i2t, const void* __restrict__ b2_i2t,
    unsigned short* __restrict__ outN, float* __restrict__ wsW) {
    int t = threadIdx.x;
    int lane = t & 63;
    int wv = t >> 6;
    // per-wave dtype probe on first 256 B of img
    unsigned int probe = ((const unsigned int*)img)[lane];
    float pa = fmaxf(__builtin_fabsf(bf2f(probe & 0xffff)),
                     __builtin_fabsf(bf2f(probe >> 16)));
    bool isF32 = __ballot(pa > 1e6f) != 0ULL;

    int row = blockIdx.x * 4 + wv;     // 0..12287
    const void* src; int srow;
    if (row < I_ * R_) { src = img; srow = row; }
    else               { src = cap; srow = row - I_ * R_; }

    float v[16];
    if (isF32) {
        const float* p = (const float*)src + (size_t)srow * D_;
        #pragma unroll
        for (int q = 0; q < 4; ++q) {
            float4 r = *(const float4*)(p + 4 * (lane + 64 * q));
            v[4 * q] = r.x; v[4 * q + 1] = r.y; v[4 * q + 2] = r.z; v[4 * q + 3] = r.w;
        }
    } else {
        const unsigned short* p = (const unsigned short*)src + (size_t)srow * D_;
        #pragma unroll
        for (int q = 0; q < 2; ++q) {
            uint4 r = *(const uint4*)(p + 8 * (lane + 64 * q));
            v[8 * q + 0] = bf2f(r.x & 0xffff); v[8 * q + 1] = bf2f(r.x >> 16);
            v[8 * q + 2] = bf2f(r.y & 0xffff); v[8 * q + 3] = bf2f(r.y >> 16);
            v[8 * q + 4] = bf2f(r.z & 0xffff); v[8 * q + 5] = bf2f(r.z >> 16);
            v[8 * q + 6] = bf2f(r.w & 0xffff); v[8 * q + 7] = bf2f(r.w >> 16);
        }
    }
    float ss = 0.f;
    #pragma unroll
    for (int q = 0; q < 16; ++q) ss += v[q] * v[q];
    ss = wave_sum(ss);
    float s = 1.0f / fmaxf(sqrtf(ss), EPSV);
    unsigned short* dst = outN + (size_t)row * D_;
    if (isF32) {
        #pragma unroll
        for (int q = 0; q < 4; ++q) {
            uint2 w;
            w.x = (unsigned)f2bf(v[4 * q] * s)     | ((unsigned)f2bf(v[4 * q + 1] * s) << 16);
            w.y = (unsigned)f2bf(v[4 * q + 2] * s) | ((unsigned)f2bf(v[4 * q + 3] * s) << 16);
            *(uint2*)(dst + 4 * (lane + 64 * q)) = w;
        }
    } else {
        #pragma unroll
        for (int q = 0; q < 2; ++q) {
            uint4 w;
            w.x = (unsigned)f2bf(v[8 * q + 0] * s) | ((unsigned)f2bf(v[8 * q + 1] * s) << 16);
            w.y = (unsigned)f2bf(v[8 * q + 2] * s) | ((unsigned)f2bf(v[8 * q + 3] * s) << 16);
            w.z = (unsigned)f2bf(v[8 * q + 4] * s) | ((unsigned)f2bf(v[8 * q + 5] * s) << 16);
            w.w = (unsigned)f2bf(v[8 * q + 6] * s) | ((unsigned)f2bf(v[8 * q + 7] * s) << 16);
            *(uint4*)(dst + 8 * (lane + 64 * q)) = w;
        }
    }
    // block 0: stage MLP weights to ws as f32
    if (blockIdx.x == 0) {
        for (int idx = t; idx < 400; idx += 256) {
            wsW[idx]       = loadw(w1_t2i, idx, isF32);
            wsW[400 + idx] = loadw(w1_i2t, idx, isF32);
        }
        if (t < 20) {
            wsW[800 + t] = loadw(b1_t2i, t, isF32);
            wsW[820 + t] = loadw(b1_i2t, t, isF32);
            wsW[840 + t] = loadw(w2_t2i, t, isF32);
            wsW[860 + t] = loadw(w2_i2t, t, isF32);
        }
        if (t == 0) { wsW[880] = loadw(b2_t2i, 0, isF32); wsW[881] = loadw(b2_i2t, 0, isF32); }
    }
}

// ========== main: DMA-staged, XOR-swizzled, CB=2 x IB=4 tile ==========
#define SSB 148      // S (bf16) row stride

struct __align__(16) Smem4 {
    union {
        struct { short A[128 * 64]; short B[144 * 64]; } st;  // 34816 B, pad-free
        unsigned short Sb[120 * SSB];                          // 35520 B
    } u;
    float nw[8][36];
    float nr[8][60];
};

__global__ __launch_bounds__(256, 4) void adj_main4(
    const unsigned short* __restrict__ capN, const unsigned short* __restrict__ imgN,
    const float* __restrict__ wsW, const int* __restrict__ cap_len,
    float* __restrict__ out) {
    __shared__ Smem4 sm;
    int tid = threadIdx.x;
    int lane = tid & 63;
    int wid = tid >> 6;
    int bx = blockIdx.x;
    int cg = bx & 63;          // XCD = cg % 8: caption slice L2-resident per XCD
    int ig = bx >> 6;
    int c0 = cg * 2;
    int i0 = ig * 4;

    float b2a = wsW[880], b2b = wsW[881];

    f32x4 acc0[9], acc1[9];
    #pragma unroll
    for (int t = 0; t < 9; ++t) {
        acc0[t] = (f32x4){0.f, 0.f, 0.f, 0.f};
        acc1[t] = (f32x4){0.f, 0.f, 0.f, 0.f};
    }

    const unsigned short* capB = capN + (size_t)c0 * 60 * D_;
    const unsigned short* imgB = imgN + (size_t)i0 * 36 * D_;

    int quad = lane >> 4;
    int l16 = lane & 15;
    int sub = lane >> 3;
    int q8 = (lane & 7) ^ sub;

    for (int kc = 0; kc < 16; ++kc) {
        int kb = kc * 64;
        #pragma unroll
        for (int u = 0; u < 4; ++u) {
            int wo = (wid << 2) + u;
            int r = (wo << 3) + sub;
            int ar = r < 120 ? r : 119;
            dma16(capB + (size_t)ar * D_ + kb + q8 * 8,
                  (char*)sm.u.st.A + (wo << 10));
        }
        for (int wo = wid; wo < 18; wo += 4) {
            int r = (wo << 3) + sub;
            dma16(imgB + (size_t)r * D_ + kb + q8 * 8,
                  (char*)sm.u.st.B + (wo << 10));
        }
        __syncthreads();   // DMA complete
        #pragma unroll
        for (int ks = 0; ks < 2; ++ks) {
            int swz = ((quad + 4 * ks) ^ (l16 & 7)) << 3;
            int rowA0 = (wid << 4) + l16;
            int rowA1 = ((wid + 4) << 4) + l16;
            bf16x8 a0 = *(const bf16x8*)(sm.u.st.A + rowA0 * 64 + swz);
            bf16x8 a1 = *(const bf16x8*)(sm.u.st.A + rowA1 * 64 + swz);
            #pragma unroll
            for (int t = 0; t < 9; ++t) {
                int rowB = (t << 4) + l16;
                bf16x8 b = *(const bf16x8*)(sm.u.st.B + rowB * 64 + swz);
                acc0[t] = __builtin_amdgcn_mfma_f32_16x16x32_bf16(a0, b, acc0[t], 0, 0, 0);
                acc1[t] = __builtin_amdgcn_mfma_f32_16x16x32_bf16(a1, b, acc1[t], 0, 0, 0);
            }
        }
        __syncthreads();   // compute done before next DMA overwrites
    }
    // leaky-relu + write S (bf16). C/D layout: col=lane&15, row=quad*4+reg
    #pragma unroll
    for (int t = 0; t < 9; ++t) {
        int col = 16 * t + l16;
        #pragma unroll
        for (int v = 0; v < 4; ++v) {
            int row0 = wid * 16 + quad * 4 + v;          // 0..63
            float x0 = acc0[t][v];
            x0 = x0 >= 0.f ? x0 : 0.1f * x0;
            sm.u.Sb[row0 * SSB + col] = f2bf(x0);
            int row1 = 64 + wid * 16 + quad * 4 + v;     // 64..127
            if (row1 < 120) {
                float x1 = acc1[t][v];
                x1 = x1 >= 0.f ? x1 : 0.1f * x1;
                sm.u.Sb[row1 * SSB + col] = f2bf(x1);
            }
        }
    }
    __syncthreads();

    // ---- epilogue: wave handles pairs p = wid, wid+4; p -> (cc, j) --------
    #pragma unroll 1
    for (int pp = 0; pp < 2; ++pp) {
        int p = wid + pp * 4;
        int cc = p >> 2, j = p & 3;
        int c = c0 + cc, i = i0 + j;
        int sbase = cc * 60;
        int cbase = j * 36;
        int L = cap_len[c];
        if (L < 1) L = 1;
        if (L > 60) L = 60;
        int Msel = L > TOPK ? L : TOPK;

        if (lane < 36) {
            float ssum = 0.f;
            for (int w = 0; w < Msel; ++w) {
                float v = bf2f(sm.u.Sb[(sbase + w) * SSB + cbase + lane]);
                ssum += v * v;
            }
            sm.nw[p][lane] = 1.0f / fmaxf(sqrtf(ssum), EPSV);
        }
        if (lane < 60) {
            float ssum = 0.f;
            for (int r = 0; r < 36; ++r) {
                float v = bf2f(sm.u.Sb[(sbase + lane) * SSB + cbase + r]);
                ssum += v * v;
            }
            sm.nr[p][lane] = 1.0f / fmaxf(sqrtf(ssum), EPSV);
        }

        // row_sim (lane = w)
        float rs = NEGV;
        if (lane < Msel) {
            float m = -3.4e38f;
            for (int r = 0; r < 36; ++r) {
                float v = bf2f(sm.u.Sb[(sbase + lane) * SSB + cbase + r]);
                m = fmaxf(m, v * sm.nw[p][r]);
            }
            rs = m;
        }
        float msum = (lane < L) ? rs : 0.f;
        msum = wave_sum(msum);
        float row_mean = msum / (float)L;

        float t2i = topk_mlp2(rs, lane, wsW, wsW + 800, wsW + 840, b2a) + row_mean;
        if (lane == 0) {
            out[(size_t)c * 128 + i] = t2i;
            out[2 * 16384 + (size_t)c * 128 + i] = row_mean;
        }

        // col_sim (lane = r)
        float cs = NEGV;
        if (lane < 36) {
            float m = -3.4e38f;
            for (int w = 0; w < L; ++w) {
                float v = bf2f(sm.u.Sb[(sbase + w) * SSB + cbase + lane]);
                m = fmaxf(m, v * sm.nr[p][w]);
            }
            cs = m;
        }
        float csum = (lane < 36) ? cs : 0.f;
        csum = wave_sum(csum);
        float col_mean = csum / 36.f;

        float i2t = topk_mlp2(cs, lane, wsW + 400, wsW + 820, wsW + 860, b2b) + col_mean;
        if (lane == 0) {
            out[16384 + (size_t)i * 128 + c] = i2t;
            out[3 * 16384 + (size_t)i * 128 + c] = col_mean;
        }
    }
}

// ================= FALLBACK (round-4 proven path, small ws) ================
__device__ inline float topk_mlp(float val, int lane,
                                 const float* __restrict__ w1,
                                 const float* __restrict__ b1,
                                 const float* __restrict__ w2, float b2v) {
    float tk[TOPK];
    #pragma unroll 1
    for (int k = 0; k < TOPK; ++k) {
        float m = wave_max(val);
        tk[k] = m;
        unsigned long long msk = __ballot(val == m);
        int first = __ffsll(msk) - 1;
        if (first >= 0 && lane == first) val = NEGV;
    }
    float contrib = 0.f;
    if (lane < TOPK) {
        float h = b1[lane];
        #pragma unroll 1
        for (int k = 0; k < TOPK; ++k)
            h += tk[k] * w1[k * TOPK + lane];
        h = fmaxf(h, 0.f);
        contrib = h * w2[lane];
    }
    contrib = wave_sum(contrib);
    return contrib + b2v;
}

__global__ void detect_dtype(const unsigned short* __restrict__ probe,
                             int* __restrict__ flag) {
    if (threadIdx.x == 0) {
        float mx = 0.f;
        for (int k = 0; k < 256; ++k) {
            float v = __builtin_fabsf(bf2f(probe[k]));
            if (v > mx) mx = v;
        }
        *flag = (mx > 1e6f) ? 1 : 0;
    }
}

__global__ __launch_bounds__(256) void rownorm_scale(
    const void* __restrict__ in, float* __restrict__ sc,
    const int* __restrict__ flag) {
    int row = blockIdx.x;
    int t = threadIdx.x;
    bool isF32 = (*flag != 0);
    float v0, v1, v2, v3;
    if (isF32) {
        const float* p = (const float*)in + (size_t)row * D_;
        float4 r = *(const float4*)(p + t * 4);
        v0 = r.x; v1 = r.y; v2 = r.z; v3 = r.w;
    } else {
        const unsigned short* p = (const unsigned short*)in + (size_t)row * D_;
        uint2 raw = *(const uint2*)(p + t * 4);
        v0 = bf2f(raw.x & 0xffff); v1 = bf2f(raw.x >> 16);
        v2 = bf2f(raw.y & 0xffff); v3 = bf2f(raw.y >> 16);
    }
    float ss = v0 * v0 + v1 * v1 + v2 * v2 + v3 * v3;
    ss = wave_sum(ss);
    __shared__ float part[4];
    if ((t & 63) == 0) part[t >> 6] = ss;
    __syncthreads();
    if (t == 0) {
        float tot = part[0] + part[1] + part[2] + part[3];
        sc[row] = 1.0f / fmaxf(sqrtf(tot), EPSV);
    }
}

#define LDA 72
#define SS 145
struct __align__(16) Smem {
    union {
        struct { short A[64 * LDA]; short B[144 * LDA]; } st;
        float S[60 * SS];
    } u;
    float scw[60];
    float sci[144];
    float nw[4][36];
    float nr[4][64];
    float w1a[400], w1b[400];
    float b1a[20], b1b[20];
    float w2a[20], w2b[20];
    float b2a, b2b;
};

__global__ __launch_bounds__(256) void adj_main(
    const void* __restrict__ capRaw, const void* __restrict__ imgRaw,
    const float* __restrict__ scCap, const float* __restrict__ scImg,
    const void* __restrict__ w1_t2i, const void* __restrict__ b1_t2i,
    const void* __restrict__ w2_t2i, const void* __restrict__ b2_t2i,
    const void* __restrict__ w1_i2t, const void* __restrict__ b1_i2t,
    const void* __restrict__ w2_i2t, const void* __restrict__ b2_i2t,
    const int* __restrict__ cap_len, const int* __restrict__ flag,
    float* __restrict__ out) {
    __shared__ Smem sm;
    int tid = threadIdx.x;
    int lane = tid & 63;
    int wid = tid >> 6;
    int bx = blockIdx.x;
    int c = bx >> 5;
    int g = bx & 31;
    int i0 = g * 4;
    bool isF32 = (*flag != 0);

    if (tid < 144) ((int*)(sm.u.st.A + 60 * LDA))[tid] = 0;
    if (tid < 60) sm.scw[tid] = scCap[c * 60 + tid];
    if (tid < 144) sm.sci[tid] = scImg[i0 * 36 + tid];
    for (int idx = tid; idx < 400; idx += 256) {
        sm.w1a[idx] = loadw(w1_t2i, idx, isF32);
        sm.w1b[idx] = loadw(w1_i2t, idx, isF32);
    }
    if (tid < 20) {
        sm.b1a[tid] = loadw(b1_t2i, tid, isF32);
        sm.b1b[tid] = loadw(b1_i2t, tid, isF32);
        sm.w2a[tid] = loadw(w2_t2i, tid, isF32);
        sm.w2b[tid] = loadw(w2_i2t, tid, isF32);
    }
    if (tid == 0) { sm.b2a = loadw(b2_t2i, 0, isF32); sm.b2b = loadw(b2_i2t, 0, isF32); }

    f32x4 acc[9];
    #pragma unroll
    for (int t = 0; t < 9; ++t) acc[t] = (f32x4){0.f, 0.f, 0.f, 0.f};

    int quad = lane >> 4;
    int l16 = lane & 15;
    int aoff = (16 * wid + l16) * LDA + quad * 8;
    int boff = l16 * LDA + quad * 8;

    for (int kc = 0; kc < 16; ++kc) {
        __syncthreads();
        int kbase = kc * 64;
        if (isF32) {
            const float* capB = (const float*)capRaw + (size_t)c * W_ * D_;
            const float* imgB = (const float*)imgRaw + (size_t)i0 * R_ * D_;
            for (int idx = tid; idx < 480; idx += 256) {
                int row = idx >> 3, ch = idx & 7;
                const float* p = capB + row * D_ + kbase + ch * 8;
                float4 x = *(const float4*)p;
                float4 y = *(const float4*)(p + 4);
                unsigned int d0 = (unsigned)f2bf(x.x) | ((unsigned)f2bf(x.y) << 16);
                unsigned int d1 = (unsigned)f2bf(x.z) | ((unsigned)f2bf(x.w) << 16);
                unsigned int d2 = (unsigned)f2bf(y.x) | ((unsigned)f2bf(y.y) << 16);
                unsigned int d3 = (unsigned)f2bf(y.z) | ((unsigned)f2bf(y.w) << 16);
                *(i32x4*)(sm.u.st.A + row * LDA + ch * 8) =
                    (i32x4){(int)d0, (int)d1, (int)d2, (int)d3};
            }
            for (int idx = tid; idx < 1152; idx += 256) {
                int row = idx >> 3, ch = idx & 7;
                const float* p = imgB + row * D_ + kbase + ch * 8;
                float4 x = *(const float4*)p;
                float4 y = *(const float4*)(p + 4);
                unsigned int d0 = (unsigned)f2bf(x.x) | ((unsigned)f2bf(x.y) << 16);
                unsigned int d1 = (unsigned)f2bf(x.z) | ((unsigned)f2bf(x.w) << 16);
                unsigned int d2 = (unsigned)f2bf(y.x) | ((unsigned)f2bf(y.y) << 16);
                unsigned int d3 = (unsigned)f2bf(y.z) | ((unsigned)f2bf(y.w) << 16);
                *(i32x4*)(sm.u.st.B + row * LDA + ch * 8) =
                    (i32x4){(int)d0, (int)d1, (int)d2, (int)d3};
            }
        } else {
            const short* capB = (const short*)capRaw + (size_t)c * W_ * D_;
            const short* imgB = (const short*)imgRaw + (size_t)i0 * R_ * D_;
            for (int idx = tid; idx < 480; idx += 256) {
                int row = idx >> 3, ch = idx & 7;
                i32x4 v = *(const i32x4*)(capB + row * D_ + kbase + ch * 8);
                *(i32x4*)(sm.u.st.A + row * LDA + ch * 8) = v;
            }
            for (int idx = tid; idx < 1152; idx += 256) {
                int row = idx >> 3, ch = idx & 7;
                i32x4 v = *(const i32x4*)(imgB + row * D_ + kbase + ch * 8);
                *(i32x4*)(sm.u.st.B + row * LDA + ch * 8) = v;
            }
        }
        __syncthreads();
        #pragma unroll
        for (int ks = 0; ks < 2; ++ks) {
            bf16x8 a = *(const bf16x8*)(sm.u.st.A + aoff + 32 * ks);
            #pragma unroll
            for (int t = 0; t < 9; ++t) {
                bf16x8 b = *(const bf16x8*)(sm.u.st.B + t * (16 * LDA) + boff + 32 * ks);
                acc[t] = __builtin_amdgcn_mfma_f32_16x16x32_bf16(a, b, acc[t], 0, 0, 0);
            }
        }
    }
    __syncthreads();
    #pragma unroll
    for (int t = 0; t < 9; ++t) {
        #pragma unroll
        for (int v = 0; v < 4; ++v) {
            int row = 16 * wid + quad * 4 + v;
            int col = 16 * t + l16;
            if (row < 60) {
                float x = acc[t][v] * sm.scw[row] * sm.sci[col];
                x = x >= 0.f ? x : 0.1f * x;
                sm.u.S[row * SS + col] = x;
            }
        }
    }
    __syncthreads();

    int j = wid;
    int i = i0 + j;
    int base = 36 * j;
    int L = cap_len[c];
    if (L < 1) L = 1;
    if (L > 60) L = 60;
    int Msel = L > TOPK ? L : TOPK;

    if (lane < 36) {
        float ssum = 0.f;
        for (int w = 0; w < Msel; ++w) {
            float v = sm.u.S[w * SS + base + lane];
            ssum += v * v;
        }
        sm.nw[j][lane] = 1.0f / fmaxf(sqrtf(ssum), EPSV);
    }
    if (lane < 60) {
        float ssum = 0.f;
        for (int r = 0; r < 36; ++r) {
            float v = sm.u.S[lane * SS + base + r];
            ssum += v * v;
        }
        sm.nr[j][lane] = 1.0f / fmaxf(sqrtf(ssum), EPSV);
    }

    float rs = NEGV;
    if (lane < Msel) {
        float m = -3.4e38f;
        for (int r = 0; r < 36; ++r) {
            float v = sm.u.S[lane * SS + base + r];
            m = fmaxf(m, v * sm.nw[j][r]);
        }
        rs = m;
    }
    float msum = (lane < L) ? rs : 0.f;
    msum = wave_sum(msum);
    float row_mean = msum / (float)L;

    float t2i = topk_mlp(rs, lane, sm.w1a, sm.b1a, sm.w2a, sm.b2a) + row_mean;
    if (lane == 0) {
        out[(size_t)c * 128 + i] = t2i;
        out[2 * 16384 + (size_t)c * 128 + i] = row_mean;
    }

    float cs = NEGV;
    if (lane < 36) {
        float m = -3.4e38f;
        for (int w = 0; w < L; ++w) {
            float v = sm.u.S[w * SS + base + lane];
            m = fmaxf(m, v * sm.nr[j][w]);
        }
        cs = m;
    }
    float csum = (lane < 36) ? cs : 0.f;
    csum = wave_sum(csum);
    float col_mean = csum / 36.f;

    float i2t = topk_mlp(cs, lane, sm.w1b, sm.b1b, sm.w2b, sm.b2b) + col_mean;
    if (lane == 0) {
        out[16384 + (size_t)i * 128 + c] = i2t;
        out[3 * 16384 + (size_t)i * 128 + c] = col_mean;
    }
}

extern "C" void kernel_launch(void* const* d_in, const int* in_sizes, int n_in,
                              void* d_out, int out_size, void* d_ws, size_t ws_size,
                              hipStream_t stream) {
    (void)in_sizes; (void)n_in; (void)out_size;
    const void* img    = d_in[0];
    const void* cap    = d_in[1];
    const int* cap_len = (const int*)d_in[10];
    float* out = (float*)d_out;

    const size_t needed = 4096 + (size_t)(I_ * R_ + C_ * W_) * D_ * 2;

    if (ws_size >= needed) {
        float* wsW = (float*)d_ws;                               // 882 f32
        unsigned short* outN = (unsigned short*)((char*)d_ws + 4096);
        const unsigned short* imgN = outN;                       // 4608 rows
        const unsigned short* capN = outN + (size_t)I_ * R_ * D_; // 7680 rows
        prep_norm3<<<(I_ * R_ + C_ * W_) / 4, 256, 0, stream>>>(
            img, cap,
            d_in[2], d_in[3], d_in[4], d_in[5],
            d_in[6], d_in[7], d_in[8], d_in[9],
            outN, wsW);
        adj_main4<<<2048, 256, 0, stream>>>(capN, imgN, wsW, cap_len, out);
    } else {
        int* flag = (int*)d_ws;
        float* scImg = (float*)d_ws + 16;
        float* scCap = scImg + I_ * R_;
        detect_dtype<<<1, 64, 0, stream>>>((const unsigned short*)img, flag);
        rownorm_scale<<<I_ * R_, 256, 0, stream>>>(img, scImg, flag);
        rownorm_scale<<<C_ * W_, 256, 0, stream>>>(cap, scCap, flag);
        adj_main<<<C_ * 32, 256, 0, stream>>>(cap, img, scCap, scImg,
                                              d_in[2], d_in[3], d_in[4], d_in[5],
                                              d_in[6], d_in[7], d_in[8], d_in[9],
                                              cap_len, flag, out);
    }
}